// Round 2
// baseline (483.393 us; speedup 1.0000x reference)
//
#include <hip/hip_runtime.h>

#define BATCH   4096
#define IN_SZ   512
#define NQ      12
#define OUT_SZ  256
#define DEPTH   3
#define NST     4096   // 2^NQ
#define BN_EPS  1e-5f

// ---- ws layout (in floats) ----
#define OFF_ENC    0            // 4096*12 = 49152
#define OFF_BN1M   49152        // 12
#define OFF_BN1R   49168        // 12 (pad to 16)
#define OFF_GU     49184        // DEPTH*NQ*8 = 288
#define OFF_GC     49472        // DEPTH*(NQ-1)*2 = 66 (pad to 96)
#define OFF_PROBS  49568        // 4096*12 = 49152
#define OFF_PMEAN  98720        // 12 (pad 16)
#define OFF_COV    98736        // 144
#define OFF_RSTD   98880        // 256
// total 99136 floats = ~397 KB

// ---------------- K0: precompute gate matrices ----------------
__global__ void k_gates(const float* __restrict__ rot, const float* __restrict__ ent,
                        float* __restrict__ gU, float* __restrict__ gC) {
    int t = threadIdx.x;
    if (t < DEPTH * NQ) {
        float ax = rot[t * 3 + 0] * 0.5f;
        float ay = rot[t * 3 + 1] * 0.5f;
        float az = rot[t * 3 + 2] * 0.5f;
        float cx = cosf(ax), sx = sinf(ax);
        float cy = cosf(ay), sy = sinf(ay);
        float cz = cosf(az), sz = sinf(az);
        // M = Ry * Rx
        float m00r =  cy * cx, m00i =  sy * sx;
        float m01r = -sy * cx, m01i = -cy * sx;
        float m10r =  sy * cx, m10i = -cy * sx;
        float m11r =  cy * cx, m11i = -sy * sx;
        // U = Rz * M ; row0 *= (cz - i sz), row1 *= (cz + i sz)
        float* o = gU + t * 8;
        o[0] = cz * m00r + sz * m00i;  o[1] = cz * m00i - sz * m00r;
        o[2] = cz * m01r + sz * m01i;  o[3] = cz * m01i - sz * m01r;
        o[4] = cz * m10r - sz * m10i;  o[5] = cz * m10i + sz * m10r;
        o[6] = cz * m11r - sz * m11i;  o[7] = cz * m11i + sz * m11r;
    }
    if (t >= 64 && t - 64 < DEPTH * (NQ - 1)) {
        int i = t - 64;
        float th = ent[i] * 0.5f;
        gC[i * 2 + 0] = cosf(th);
        gC[i * 2 + 1] = sinf(th);
    }
}

// ---------------- K1: encoded = x @ enc_w.T + enc_b ----------------
__global__ void k_encode(const float* __restrict__ x, const float* __restrict__ w,
                         const float* __restrict__ bvec, float* __restrict__ enc) {
    int gi = blockIdx.x * 256 + threadIdx.x;           // < BATCH*NQ
    if (gi >= BATCH * NQ) return;
    int row = gi / NQ;
    int q   = gi - row * NQ;
    const float4* xr = (const float4*)(x + row * IN_SZ);
    const float4* wr = (const float4*)(w + q * IN_SZ);
    float acc = 0.f;
    for (int k = 0; k < IN_SZ / 4; k++) {
        float4 xv = xr[k];
        float4 wv = wr[k];
        acc += xv.x * wv.x + xv.y * wv.y + xv.z * wv.z + xv.w * wv.w;
    }
    enc[gi] = acc + bvec[q];
}

// ---------------- block-wide sum (result broadcast to all threads) ----------------
__device__ float blockAllSum(float v, float* scr) {
    #pragma unroll
    for (int o = 32; o > 0; o >>= 1) v += __shfl_down(v, o, 64);
    int lane = threadIdx.x & 63, w = threadIdx.x >> 6;
    __syncthreads();                 // protect scr reuse across calls
    if (lane == 0) scr[w] = v;
    __syncthreads();
    return scr[0] + scr[1] + scr[2] + scr[3];
}

// ---------------- K2: batchnorm1 stats (one block per feature) ----------------
__global__ void k_bnstats(const float* __restrict__ xm, float* __restrict__ mo,
                          float* __restrict__ ro, int ncols, int nrows) {
    __shared__ float scr[8];
    int j = blockIdx.x, t = threadIdx.x;
    float s = 0.f;
    for (int b = t; b < nrows; b += 256) s += xm[b * ncols + j];
    float mean = blockAllSum(s, scr) / (float)nrows;
    float s2 = 0.f;
    for (int b = t; b < nrows; b += 256) {
        float d = xm[b * ncols + j] - mean;
        s2 += d * d;
    }
    float var = blockAllSum(s2, scr) / (float)nrows;
    if (t == 0) {
        mo[j] = mean;
        ro[j] = 1.f / sqrtf(var + BN_EPS);
    }
}

// ---------------- K3: quantum circuit simulation (one block per batch element) ----------------
__launch_bounds__(256)
__global__ void k_quantum(const float* __restrict__ enc,
                          const float* __restrict__ bn1m, const float* __restrict__ bn1r,
                          const float* __restrict__ g1, const float* __restrict__ b1,
                          const float* __restrict__ gU, const float* __restrict__ gC,
                          float* __restrict__ probs) {
    __shared__ float2 st[NST];                       // 32 KB
    __shared__ float  gbuf[DEPTH * NQ * 8 + DEPTH * (NQ - 1) * 2];  // 354
    __shared__ float  qv[NQ][2];
    __shared__ float  hbuf[NQ];
    __shared__ float  red[4][NQ];

    int t = threadIdx.x, b = blockIdx.x;

    for (int i = t; i < 354; i += 256) gbuf[i] = (i < 288) ? gU[i] : gC[i - 288];

    if (t < NQ) {
        float e = enc[b * NQ + t];
        hbuf[t] = tanhf(g1[t] * (e - bn1m[t]) * bn1r[t] + b1[t]);
    }
    __syncthreads();
    if (t < NQ) {
        float n2 = 0.f;
        #pragma unroll
        for (int i = 0; i < NQ; i++) n2 += hbuf[i] * hbuf[i];
        float norm = sqrtf(n2);
        float h = hbuf[t];
        float a = (norm > 0.f) ? h / fmaxf(norm, 1e-30f) : h;
        float amp = fminf(fabsf(a), 1.f);
        float ch  = sqrtf(fmaxf(1.f - amp * amp, 0.f));
        qv[t][0] = ch;
        qv[t][1] = (a < 0.f) ? -amp : amp;
    }
    __syncthreads();

    // initial product state (real). qubit q lives at bit (11-q).
    for (int idx = t; idx < NST; idx += 256) {
        float p = 1.f;
        #pragma unroll
        for (int q = 0; q < NQ; q++) p *= qv[q][(idx >> (11 - q)) & 1];
        st[idx] = make_float2(p, 0.f);
    }

    #pragma unroll 1
    for (int l = 0; l < DEPTH; l++) {
        // single-qubit gates
        #pragma unroll 1
        for (int q = 0; q < NQ; q++) {
            __syncthreads();
            const float* u = &gbuf[(l * NQ + q) * 8];
            float u00r = u[0], u00i = u[1], u01r = u[2], u01i = u[3];
            float u10r = u[4], u10i = u[5], u11r = u[6], u11i = u[7];
            int p   = 11 - q;
            int mlo = (1 << p) - 1;
            #pragma unroll
            for (int k = 0; k < 8; k++) {
                int pi = (k << 8) | t;                       // pair index, 2048 pairs
                int i0 = ((pi & ~mlo) << 1) | (pi & mlo);
                int i1 = i0 | (1 << p);
                float2 a0 = st[i0], a1 = st[i1];
                float n0r = u00r * a0.x - u00i * a0.y + u01r * a1.x - u01i * a1.y;
                float n0i = u00r * a0.y + u00i * a0.x + u01r * a1.y + u01i * a1.x;
                float n1r = u10r * a0.x - u10i * a0.y + u11r * a1.x - u11i * a1.y;
                float n1i = u10r * a0.y + u10i * a0.x + u11r * a1.y + u11i * a1.x;
                st[i0] = make_float2(n0r, n0i);
                st[i1] = make_float2(n1r, n1i);
            }
        }
        // CRY chain: control qubit q (bit 11-q), target q+1 (bit 10-q)
        #pragma unroll 1
        for (int q = 0; q < NQ - 1; q++) {
            __syncthreads();
            float c = gbuf[288 + (l * (NQ - 1) + q) * 2];
            float s = gbuf[288 + (l * (NQ - 1) + q) * 2 + 1];
            int pt  = 10 - q;
            int mlo = (1 << pt) - 1;
            #pragma unroll
            for (int k = 0; k < 4; k++) {
                int pi = (k << 8) | t;                       // 1024 pairs (control==1)
                int i0 = ((pi & ~mlo) << 2) | (2 << pt) | (pi & mlo);
                int i1 = i0 | (1 << pt);
                float2 a0 = st[i0], a1 = st[i1];
                st[i0] = make_float2(c * a0.x - s * a1.x, c * a0.y - s * a1.y);
                st[i1] = make_float2(s * a0.x + c * a1.x, s * a0.y + c * a1.y);
            }
        }
    }
    __syncthreads();

    // marginals: probs[b][j] = sum_idx |st[idx]|^2 * bit_{11-j}(idx)
    float acc[NQ];
    #pragma unroll
    for (int j = 0; j < NQ; j++) acc[j] = 0.f;
    for (int idx = t; idx < NST; idx += 256) {
        float2 v = st[idx];
        float pr = v.x * v.x + v.y * v.y;
        #pragma unroll
        for (int j = 0; j < NQ; j++) acc[j] += ((idx >> (11 - j)) & 1) ? pr : 0.f;
    }
    #pragma unroll
    for (int j = 0; j < NQ; j++) {
        #pragma unroll
        for (int o = 32; o > 0; o >>= 1) acc[j] += __shfl_down(acc[j], o, 64);
    }
    int lane = t & 63, w = t >> 6;
    if (lane == 0) {
        #pragma unroll
        for (int j = 0; j < NQ; j++) red[w][j] = acc[j];
    }
    __syncthreads();
    if (t < NQ) probs[b * NQ + t] = red[0][t] + red[1][t] + red[2][t] + red[3][t];
}

// ---------------- K4: mean of probs per qubit (12 blocks) ----------------
__global__ void k_pmean(const float* __restrict__ probs, float* __restrict__ pmean) {
    __shared__ float scr[8];
    int j = blockIdx.x, t = threadIdx.x;
    float s = 0.f;
    for (int b = t; b < BATCH; b += 256) s += probs[b * NQ + j];
    float mean = blockAllSum(s, scr) / (float)BATCH;
    if (t == 0) pmean[j] = mean;
}

// ---------------- K5: covariance of probs (144 blocks) ----------------
__global__ void k_pcov(const float* __restrict__ probs, const float* __restrict__ pmean,
                       float* __restrict__ cov) {
    __shared__ float scr[8];
    int blk = blockIdx.x;             // 0..143
    int q  = blk / NQ, q2 = blk % NQ;
    int t = threadIdx.x;
    float mq = pmean[q], mq2 = pmean[q2];
    float s = 0.f;
    for (int b = t; b < BATCH; b += 256)
        s += (probs[b * NQ + q] - mq) * (probs[b * NQ + q2] - mq2);
    float c = blockAllSum(s, scr) / (float)BATCH;
    if (t == 0) cov[blk] = c;
}

// ---------------- K6: per-output-feature rstd: var = w^T Cov w ----------------
__global__ void k_outstats(const float* __restrict__ cov, const float* __restrict__ dw,
                           float* __restrict__ rstd) {
    __shared__ float cv[NQ * NQ];
    int t = threadIdx.x;              // 0..255 = output feature
    if (t < NQ * NQ) cv[t] = cov[t];
    __syncthreads();
    float w[NQ];
    #pragma unroll
    for (int q = 0; q < NQ; q++) w[q] = dw[t * NQ + q];
    float var = 0.f;
    #pragma unroll
    for (int q = 0; q < NQ; q++) {
        float a = 0.f;
        #pragma unroll
        for (int q2 = 0; q2 < NQ; q2++) a += cv[q * NQ + q2] * w[q2];
        var += w[q] * a;
    }
    rstd[t] = 1.f / sqrtf(var + BN_EPS);
}

// ---------------- K7: final decode + BN2 (one block per batch row) ----------------
// out[b,j] = (sum_q dw[j,q]*(p[b,q]-pmean[q])) * rstd[j] * g2[j] + b2[j]
__global__ void k_final(const float* __restrict__ probs, const float* __restrict__ pmean,
                        const float* __restrict__ dw, const float* __restrict__ rstd,
                        const float* __restrict__ g2, const float* __restrict__ b2,
                        float* __restrict__ out) {
    __shared__ float cp[NQ];
    int b = blockIdx.x, t = threadIdx.x;      // t = output feature (256)
    if (t < NQ) cp[t] = probs[b * NQ + t] - pmean[t];
    __syncthreads();
    float acc = 0.f;
    #pragma unroll
    for (int q = 0; q < NQ; q++) acc += cp[q] * dw[t * NQ + q];
    out[b * OUT_SZ + t] = acc * rstd[t] * g2[t] + b2[t];
}

extern "C" void kernel_launch(void* const* d_in, const int* in_sizes, int n_in,
                              void* d_out, int out_size, void* d_ws, size_t ws_size,
                              hipStream_t stream) {
    const float* x     = (const float*)d_in[0];
    const float* enc_w = (const float*)d_in[1];
    const float* enc_b = (const float*)d_in[2];
    const float* rot   = (const float*)d_in[3];
    const float* ent   = (const float*)d_in[4];
    const float* dec_w = (const float*)d_in[5];
    // d_in[6] = dec_b — cancels inside BN2, unused
    const float* g1    = (const float*)d_in[7];
    const float* b1    = (const float*)d_in[8];
    const float* g2    = (const float*)d_in[9];
    const float* b2    = (const float*)d_in[10];

    float* ws    = (float*)d_ws;
    float* enc   = ws + OFF_ENC;
    float* bn1m  = ws + OFF_BN1M;
    float* bn1r  = ws + OFF_BN1R;
    float* gU    = ws + OFF_GU;
    float* gC    = ws + OFF_GC;
    float* prb   = ws + OFF_PROBS;
    float* pmean = ws + OFF_PMEAN;
    float* cov   = ws + OFF_COV;
    float* rstd  = ws + OFF_RSTD;

    hipLaunchKernelGGL(k_gates, dim3(1), dim3(128), 0, stream, rot, ent, gU, gC);
    hipLaunchKernelGGL(k_encode, dim3((BATCH * NQ + 255) / 256), dim3(256), 0, stream,
                       x, enc_w, enc_b, enc);
    hipLaunchKernelGGL(k_bnstats, dim3(NQ), dim3(256), 0, stream, enc, bn1m, bn1r, NQ, BATCH);
    hipLaunchKernelGGL(k_quantum, dim3(BATCH), dim3(256), 0, stream,
                       enc, bn1m, bn1r, g1, b1, gU, gC, prb);
    hipLaunchKernelGGL(k_pmean, dim3(NQ), dim3(256), 0, stream, prb, pmean);
    hipLaunchKernelGGL(k_pcov, dim3(NQ * NQ), dim3(256), 0, stream, prb, pmean, cov);
    hipLaunchKernelGGL(k_outstats, dim3(1), dim3(OUT_SZ), 0, stream, cov, dec_w, rstd);
    hipLaunchKernelGGL(k_final, dim3(BATCH), dim3(OUT_SZ), 0, stream,
                       prb, pmean, dec_w, rstd, g2, b2, (float*)d_out);
}

// Round 3
// 380.876 us; speedup vs baseline: 1.2692x; 1.2692x over previous
//
#include <hip/hip_runtime.h>

#define BATCH   4096
#define IN_SZ   512
#define NQ      12
#define OUT_SZ  256
#define DEPTH   3
#define NST     4096   // 2^NQ
#define BN_EPS  1e-5f

// ---- ws layout (in floats) ----
#define OFF_ENC    0            // 4096*12 = 49152
#define OFF_BN1M   49152        // 12 (pad 16)
#define OFF_BN1R   49168        // 12 (pad 16)
#define OFF_GU     49184        // DEPTH*NQ*8 = 288
#define OFF_GC     49472        // DEPTH*(NQ-1)*2 = 66 (pad 96)
#define OFF_PROBS  49568        // 4096*12 = 49152
#define OFF_PMEAN  98720        // 12 (pad 16)
#define OFF_COV    98736        // 144
// total ~99 K floats = ~397 KB

// ================= K1: encode (+ fused gate precompute in block 192) =================
__global__ void k_encode(const float* __restrict__ x, const float* __restrict__ w,
                         const float* __restrict__ bvec,
                         const float* __restrict__ rot, const float* __restrict__ ent,
                         float* __restrict__ enc, float* __restrict__ gU, float* __restrict__ gC) {
    if (blockIdx.x == 192) {
        int t = threadIdx.x;
        if (t < DEPTH * NQ) {
            float ax = rot[t * 3 + 0] * 0.5f;
            float ay = rot[t * 3 + 1] * 0.5f;
            float az = rot[t * 3 + 2] * 0.5f;
            float cx = cosf(ax), sx = sinf(ax);
            float cy = cosf(ay), sy = sinf(ay);
            float cz = cosf(az), sz = sinf(az);
            // M = Ry * Rx
            float m00r =  cy * cx, m00i =  sy * sx;
            float m01r = -sy * cx, m01i = -cy * sx;
            float m10r =  sy * cx, m10i = -cy * sx;
            float m11r =  cy * cx, m11i = -sy * sx;
            // U = Rz * M
            float* o = gU + t * 8;
            o[0] = cz * m00r + sz * m00i;  o[1] = cz * m00i - sz * m00r;
            o[2] = cz * m01r + sz * m01i;  o[3] = cz * m01i - sz * m01r;
            o[4] = cz * m10r - sz * m10i;  o[5] = cz * m10i + sz * m10r;
            o[6] = cz * m11r - sz * m11i;  o[7] = cz * m11i + sz * m11r;
        }
        if (t >= 64 && t - 64 < DEPTH * (NQ - 1)) {
            int i = t - 64;
            float th = ent[i] * 0.5f;
            gC[i * 2 + 0] = cosf(th);
            gC[i * 2 + 1] = sinf(th);
        }
        return;
    }
    int gi = blockIdx.x * 256 + threadIdx.x;           // < BATCH*NQ
    int row = gi / NQ;
    int q   = gi - row * NQ;
    const float4* xr = (const float4*)(x + row * IN_SZ);
    const float4* wr = (const float4*)(w + q * IN_SZ);
    float acc = 0.f;
    for (int k = 0; k < IN_SZ / 4; k++) {
        float4 xv = xr[k];
        float4 wv = wr[k];
        acc += xv.x * wv.x + xv.y * wv.y + xv.z * wv.z + xv.w * wv.w;
    }
    enc[gi] = acc + bvec[q];
}

// ---------------- block-wide sum (result broadcast) ----------------
__device__ float blockAllSum(float v, float* scr) {
    #pragma unroll
    for (int o = 32; o > 0; o >>= 1) v += __shfl_down(v, o, 64);
    int lane = threadIdx.x & 63, w = threadIdx.x >> 6;
    __syncthreads();
    if (lane == 0) scr[w] = v;
    __syncthreads();
    return scr[0] + scr[1] + scr[2] + scr[3];
}

// ================= K2: batchnorm1 stats =================
__global__ void k_bnstats(const float* __restrict__ xm, float* __restrict__ mo,
                          float* __restrict__ ro, int ncols, int nrows) {
    __shared__ float scr[8];
    int j = blockIdx.x, t = threadIdx.x;
    float s = 0.f;
    for (int b = t; b < nrows; b += 256) s += xm[b * ncols + j];
    float mean = blockAllSum(s, scr) / (float)nrows;
    float s2 = 0.f;
    for (int b = t; b < nrows; b += 256) {
        float d = xm[b * ncols + j] - mean;
        s2 += d * d;
    }
    float var = blockAllSum(s2, scr) / (float)nrows;
    if (t == 0) {
        mo[j] = mean;
        ro[j] = 1.f / sqrtf(var + BN_EPS);
    }
}

// ================= K3: quantum circuit, register-resident state =================
// Amp index bit (11-q) holds qubit q.
// Layout A: idx = T<<4 | j      (local nibble = bits 3..0  -> qubits 8..11)
// Layout B: idx = T[7:4]<<8 | j<<4 | T[3:0]  (local = bits 7..4 -> qubits 4..7)
// Layout C: idx = j<<8 | T      (local = bits 11..8 -> qubits 0..3)
__device__ __forceinline__ int slotA(int T, int j) { return (T << 4) | (j ^ (T & 0xF)); }
__device__ __forceinline__ int slotB(int T, int j) {
    return ((T & 0xF0) << 4) | (j << 4) | ((T ^ j) & 0xF);
}
__device__ __forceinline__ int slotC(int T, int j) {
    return (j << 8) | (T & 0xF0) | (((T >> 4) ^ T) & 0xF);
}

template<int K>
__device__ __forceinline__ void apply_u(float2* s, const float* u) {
    float u00r = u[0], u00i = u[1], u01r = u[2], u01i = u[3];
    float u10r = u[4], u10i = u[5], u11r = u[6], u11i = u[7];
    #pragma unroll
    for (int m = 0; m < 16; m++) {
        if (m & (1 << K)) continue;
        int j1 = m | (1 << K);
        float2 a0 = s[m], a1 = s[j1];
        s[m]  = make_float2(u00r * a0.x - u00i * a0.y + u01r * a1.x - u01i * a1.y,
                            u00r * a0.y + u00i * a0.x + u01r * a1.y + u01i * a1.x);
        s[j1] = make_float2(u10r * a0.x - u10i * a0.y + u11r * a1.x - u11i * a1.y,
                            u10r * a0.y + u10i * a0.x + u11r * a1.y + u11i * a1.x);
    }
}

template<int KC, int KT>
__device__ __forceinline__ void apply_cry_local(float2* s, float c, float sn) {
    #pragma unroll
    for (int m = 0; m < 16; m++) {
        if (!(m & (1 << KC)) || (m & (1 << KT))) continue;
        int j1 = m | (1 << KT);
        float2 a0 = s[m], a1 = s[j1];
        s[m]  = make_float2(c * a0.x - sn * a1.x, c * a0.y - sn * a1.y);
        s[j1] = make_float2(sn * a0.x + c * a1.x, sn * a0.y + c * a1.y);
    }
}

template<int KT>
__device__ __forceinline__ void apply_ry_all(float2* s, float c, float sn) {
    #pragma unroll
    for (int m = 0; m < 16; m++) {
        if (m & (1 << KT)) continue;
        int j1 = m | (1 << KT);
        float2 a0 = s[m], a1 = s[j1];
        s[m]  = make_float2(c * a0.x - sn * a1.x, c * a0.y - sn * a1.y);
        s[j1] = make_float2(sn * a0.x + c * a1.x, sn * a0.y + c * a1.y);
    }
}

#define XPOSE(SW, SR) do {                                        \
    __syncthreads();                                              \
    _Pragma("unroll") for (int j = 0; j < 16; j++) xch[SW(T, j)] = s[j]; \
    __syncthreads();                                              \
    _Pragma("unroll") for (int j = 0; j < 16; j++) s[j] = xch[SR(T, j)]; \
} while (0)

__launch_bounds__(256, 4)
__global__ void k_quantum(const float* __restrict__ enc,
                          const float* __restrict__ bn1m, const float* __restrict__ bn1r,
                          const float* __restrict__ g1, const float* __restrict__ b1,
                          const float* __restrict__ gU, const float* __restrict__ gC,
                          float* __restrict__ probs) {
    __shared__ float2 xch[NST];                                  // 32 KB
    __shared__ float  gbuf[DEPTH * NQ * 8 + DEPTH * (NQ - 1) * 2];  // 354
    __shared__ float  qv[NQ][2];
    __shared__ float  hbuf[NQ];

    int T = threadIdx.x, b = blockIdx.x;

    for (int i = T; i < 354; i += 256) gbuf[i] = (i < 288) ? gU[i] : gC[i - 288];

    if (T < NQ) {
        float e = enc[b * NQ + T];
        hbuf[T] = tanhf(g1[T] * (e - bn1m[T]) * bn1r[T] + b1[T]);
    }
    __syncthreads();
    if (T < NQ) {
        float n2 = 0.f;
        #pragma unroll
        for (int i = 0; i < NQ; i++) n2 += hbuf[i] * hbuf[i];
        float norm = sqrtf(n2);
        float h = hbuf[T];
        float a = (norm > 0.f) ? h / fmaxf(norm, 1e-30f) : h;
        float amp = fminf(fabsf(a), 1.f);
        float ch  = sqrtf(fmaxf(1.f - amp * amp, 0.f));
        qv[T][0] = ch;
        qv[T][1] = (a < 0.f) ? -amp : amp;
    }
    __syncthreads();

    // ---- initial product state, layout A ----
    float f = 1.f;
    #pragma unroll
    for (int q = 0; q < 8; q++) f *= qv[q][(T >> (7 - q)) & 1];
    float2 s[16];
    #pragma unroll
    for (int j = 0; j < 16; j++) {
        float p = f * qv[8][(j >> 3) & 1] * qv[9][(j >> 2) & 1]
                    * qv[10][(j >> 1) & 1] * qv[11][j & 1];
        s[j] = make_float2(p, 0.f);
    }

    #pragma unroll 1
    for (int l = 0; l < DEPTH; l++) {
        const float* UL = &gbuf[l * NQ * 8];
        const float* CL = &gbuf[288 + l * (NQ - 1) * 2];
        // layout A: U on qubits 8..11 (local bits 3..0)
        apply_u<3>(s, UL + 8 * 8);
        apply_u<2>(s, UL + 9 * 8);
        apply_u<1>(s, UL + 10 * 8);
        apply_u<0>(s, UL + 11 * 8);
        XPOSE(slotA, slotB);
        // layout B: U on qubits 4..7 (local bits 3..0 = idx bits 7..4)
        apply_u<3>(s, UL + 4 * 8);
        apply_u<2>(s, UL + 5 * 8);
        apply_u<1>(s, UL + 6 * 8);
        apply_u<0>(s, UL + 7 * 8);
        XPOSE(slotB, slotC);
        // layout C: U on qubits 0..3; CRY0..2
        apply_u<3>(s, UL + 0 * 8);
        apply_u<2>(s, UL + 1 * 8);
        apply_u<1>(s, UL + 2 * 8);
        apply_u<0>(s, UL + 3 * 8);
        apply_cry_local<3, 2>(s, CL[0], CL[1]);     // CRY0
        apply_cry_local<2, 1>(s, CL[2], CL[3]);     // CRY1
        apply_cry_local<1, 0>(s, CL[4], CL[5]);     // CRY2
        XPOSE(slotC, slotB);
        // layout B: CRY3..6 (CRY3 control = idx bit 8 = T[4])
        if (T & 16) apply_ry_all<3>(s, CL[6], CL[7]);   // CRY3
        apply_cry_local<3, 2>(s, CL[8], CL[9]);     // CRY4
        apply_cry_local<2, 1>(s, CL[10], CL[11]);   // CRY5
        apply_cry_local<1, 0>(s, CL[12], CL[13]);   // CRY6
        XPOSE(slotB, slotA);
        // layout A: CRY7..10 (CRY7 control = idx bit 4 = T[0])
        if (T & 1) apply_ry_all<3>(s, CL[14], CL[15]);  // CRY7
        apply_cry_local<3, 2>(s, CL[16], CL[17]);   // CRY8
        apply_cry_local<2, 1>(s, CL[18], CL[19]);   // CRY9
        apply_cry_local<1, 0>(s, CL[20], CL[21]);   // CRY10
    }

    // ---- marginals, layout A: idx = T<<4 | j ----
    float acc[NQ];
    float tot = 0.f;
    #pragma unroll
    for (int q = 8; q < NQ; q++) acc[q] = 0.f;
    #pragma unroll
    for (int j = 0; j < 16; j++) {
        float pr = s[j].x * s[j].x + s[j].y * s[j].y;
        tot += pr;
        if (j & 8) acc[8]  += pr;
        if (j & 4) acc[9]  += pr;
        if (j & 2) acc[10] += pr;
        if (j & 1) acc[11] += pr;
    }
    #pragma unroll
    for (int q = 0; q < 8; q++) acc[q] = ((T >> (7 - q)) & 1) ? tot : 0.f;

    #pragma unroll
    for (int q = 0; q < NQ; q++) {
        #pragma unroll
        for (int o = 32; o > 0; o >>= 1) acc[q] += __shfl_down(acc[q], o, 64);
    }
    __syncthreads();                     // xch no longer needed as state
    float* red = (float*)xch;
    int lane = T & 63, w = T >> 6;
    if (lane == 0) {
        #pragma unroll
        for (int q = 0; q < NQ; q++) red[w * NQ + q] = acc[q];
    }
    __syncthreads();
    if (T < NQ) probs[b * NQ + T] = red[T] + red[NQ + T] + red[2 * NQ + T] + red[3 * NQ + T];
}

// ================= K4: prob moments -> pmean + cov (one pass) =================
__global__ void k_pcov(const float* __restrict__ probs, float* __restrict__ pmean,
                       float* __restrict__ cov) {
    __shared__ float scr[8];
    int blk = blockIdx.x;             // 0..143
    int q = blk / NQ, q2 = blk % NQ;
    int t = threadIdx.x;
    float sx = 0.f, sy = 0.f, sxy = 0.f;
    for (int b = t; b < BATCH; b += 256) {
        float xv = probs[b * NQ + q];
        float yv = probs[b * NQ + q2];
        sx += xv; sy += yv; sxy += xv * yv;
    }
    float SX  = blockAllSum(sx,  scr);
    float SY  = blockAllSum(sy,  scr);
    float SXY = blockAllSum(sxy, scr);
    if (t == 0) {
        float mx = SX / (float)BATCH, my = SY / (float)BATCH;
        cov[blk] = SXY / (float)BATCH - mx * my;
        if (q == q2) pmean[q] = mx;
    }
}

// ================= K5: final decode + BN2 (rstd computed per-thread from cov) =================
// out[b,j] = (sum_q dw[j,q]*(p[b,q]-pmean[q])) * rstd[j] * g2[j] + b2[j], rstd = 1/sqrt(w^T C w + eps)
__global__ void k_final(const float* __restrict__ probs, const float* __restrict__ pmean,
                        const float* __restrict__ cov, const float* __restrict__ dw,
                        const float* __restrict__ g2, const float* __restrict__ b2,
                        float* __restrict__ out) {
    __shared__ float cv[NQ * NQ];
    __shared__ float cp[NQ];
    int b = blockIdx.x, t = threadIdx.x;      // t = output feature
    if (t < NQ * NQ) cv[t] = cov[t];
    if (t < NQ) cp[t] = probs[b * NQ + t] - pmean[t];
    __syncthreads();
    float w[NQ];
    #pragma unroll
    for (int q = 0; q < NQ; q++) w[q] = dw[t * NQ + q];
    float var = 0.f, acc = 0.f;
    #pragma unroll
    for (int q = 0; q < NQ; q++) {
        float a = 0.f;
        #pragma unroll
        for (int q2 = 0; q2 < NQ; q2++) a += cv[q * NQ + q2] * w[q2];
        var += w[q] * a;
        acc += cp[q] * w[q];
    }
    out[b * OUT_SZ + t] = acc * (1.f / sqrtf(var + BN_EPS)) * g2[t] + b2[t];
}

extern "C" void kernel_launch(void* const* d_in, const int* in_sizes, int n_in,
                              void* d_out, int out_size, void* d_ws, size_t ws_size,
                              hipStream_t stream) {
    const float* x     = (const float*)d_in[0];
    const float* enc_w = (const float*)d_in[1];
    const float* enc_b = (const float*)d_in[2];
    const float* rot   = (const float*)d_in[3];
    const float* ent   = (const float*)d_in[4];
    const float* dec_w = (const float*)d_in[5];
    // d_in[6] = dec_b — cancels inside BN2
    const float* g1    = (const float*)d_in[7];
    const float* b1    = (const float*)d_in[8];
    const float* g2    = (const float*)d_in[9];
    const float* b2    = (const float*)d_in[10];

    float* ws    = (float*)d_ws;
    float* enc   = ws + OFF_ENC;
    float* bn1m  = ws + OFF_BN1M;
    float* bn1r  = ws + OFF_BN1R;
    float* gU    = ws + OFF_GU;
    float* gC    = ws + OFF_GC;
    float* prb   = ws + OFF_PROBS;
    float* pmean = ws + OFF_PMEAN;
    float* cov   = ws + OFF_COV;

    hipLaunchKernelGGL(k_encode, dim3(193), dim3(256), 0, stream,
                       x, enc_w, enc_b, rot, ent, enc, gU, gC);
    hipLaunchKernelGGL(k_bnstats, dim3(NQ), dim3(256), 0, stream, enc, bn1m, bn1r, NQ, BATCH);
    hipLaunchKernelGGL(k_quantum, dim3(BATCH), dim3(256), 0, stream,
                       enc, bn1m, bn1r, g1, b1, gU, gC, prb);
    hipLaunchKernelGGL(k_pcov, dim3(NQ * NQ), dim3(256), 0, stream, prb, pmean, cov);
    hipLaunchKernelGGL(k_final, dim3(BATCH), dim3(OUT_SZ), 0, stream,
                       prb, pmean, cov, dec_w, g2, b2, (float*)d_out);
}

// Round 4
// 373.478 us; speedup vs baseline: 1.2943x; 1.0198x over previous
//
#include <hip/hip_runtime.h>

#define BATCH   4096
#define IN_SZ   512
#define NQ      12
#define OUT_SZ  256
#define DEPTH   3
#define NST     4096   // 2^NQ
#define BN_EPS  1e-5f

// ---- ws layout (in floats) ----
#define OFF_ENC    0            // 4096*12 = 49152
#define OFF_BN1M   49152        // 12 (pad 16)
#define OFF_BN1R   49168        // 12 (pad 16)
#define OFF_GU     49184        // DEPTH*NQ*8 = 288
#define OFF_GC     49472        // DEPTH*(NQ-1)*2 = 66 (pad 96)
#define OFF_PROBS  49568        // 4096*12 = 49152
#define OFF_PMEAN  98720        // 12 (pad 16)
#define OFF_COV    98736        // 144
// total ~99 K floats = ~397 KB

// ================= K1: encode (+ fused gate precompute in block 192) =================
__global__ void k_encode(const float* __restrict__ x, const float* __restrict__ w,
                         const float* __restrict__ bvec,
                         const float* __restrict__ rot, const float* __restrict__ ent,
                         float* __restrict__ enc, float* __restrict__ gU, float* __restrict__ gC) {
    if (blockIdx.x == 192) {
        int t = threadIdx.x;
        if (t < DEPTH * NQ) {
            float ax = rot[t * 3 + 0] * 0.5f;
            float ay = rot[t * 3 + 1] * 0.5f;
            float az = rot[t * 3 + 2] * 0.5f;
            float cx = cosf(ax), sx = sinf(ax);
            float cy = cosf(ay), sy = sinf(ay);
            float cz = cosf(az), sz = sinf(az);
            // M = Ry * Rx
            float m00r =  cy * cx, m00i =  sy * sx;
            float m01r = -sy * cx, m01i = -cy * sx;
            float m10r =  sy * cx, m10i = -cy * sx;
            float m11r =  cy * cx, m11i = -sy * sx;
            // U = Rz * M
            float* o = gU + t * 8;
            o[0] = cz * m00r + sz * m00i;  o[1] = cz * m00i - sz * m00r;
            o[2] = cz * m01r + sz * m01i;  o[3] = cz * m01i - sz * m01r;
            o[4] = cz * m10r - sz * m10i;  o[5] = cz * m10i + sz * m10r;
            o[6] = cz * m11r - sz * m11i;  o[7] = cz * m11i + sz * m11r;
        }
        if (t >= 64 && t - 64 < DEPTH * (NQ - 1)) {
            int i = t - 64;
            float th = ent[i] * 0.5f;
            gC[i * 2 + 0] = cosf(th);
            gC[i * 2 + 1] = sinf(th);
        }
        return;
    }
    int gi = blockIdx.x * 256 + threadIdx.x;           // < BATCH*NQ
    int row = gi / NQ;
    int q   = gi - row * NQ;
    const float4* xr = (const float4*)(x + row * IN_SZ);
    const float4* wr = (const float4*)(w + q * IN_SZ);
    float acc = 0.f;
    for (int k = 0; k < IN_SZ / 4; k++) {
        float4 xv = xr[k];
        float4 wv = wr[k];
        acc += xv.x * wv.x + xv.y * wv.y + xv.z * wv.z + xv.w * wv.w;
    }
    enc[gi] = acc + bvec[q];
}

// ---------------- block-wide sum (result broadcast) ----------------
__device__ float blockAllSum(float v, float* scr) {
    #pragma unroll
    for (int o = 32; o > 0; o >>= 1) v += __shfl_down(v, o, 64);
    int lane = threadIdx.x & 63, w = threadIdx.x >> 6;
    __syncthreads();
    if (lane == 0) scr[w] = v;
    __syncthreads();
    return scr[0] + scr[1] + scr[2] + scr[3];
}

// ================= K2: batchnorm1 stats =================
__global__ void k_bnstats(const float* __restrict__ xm, float* __restrict__ mo,
                          float* __restrict__ ro, int ncols, int nrows) {
    __shared__ float scr[8];
    int j = blockIdx.x, t = threadIdx.x;
    float s = 0.f;
    for (int b = t; b < nrows; b += 256) s += xm[b * ncols + j];
    float mean = blockAllSum(s, scr) / (float)nrows;
    float s2 = 0.f;
    for (int b = t; b < nrows; b += 256) {
        float d = xm[b * ncols + j] - mean;
        s2 += d * d;
    }
    float var = blockAllSum(s2, scr) / (float)nrows;
    if (t == 0) {
        mo[j] = mean;
        ro[j] = 1.f / sqrtf(var + BN_EPS);
    }
}

// ================= K3: quantum circuit, register-resident state =================
// Amp index bit (11-q) holds qubit q.
// Layout A: idx = T<<4 | j      (local nibble = bits 3..0  -> qubits 8..11)
// Layout B: idx = T[7:4]<<8 | j<<4 | T[3:0]  (local = bits 7..4 -> qubits 4..7)
// Layout C: idx = j<<8 | T      (local = bits 11..8 -> qubits 0..3)
__device__ __forceinline__ int slotA(int T, int j) { return (T << 4) | (j ^ (T & 0xF)); }
__device__ __forceinline__ int slotB(int T, int j) {
    return ((T & 0xF0) << 4) | (j << 4) | ((T ^ j) & 0xF);
}
__device__ __forceinline__ int slotC(int T, int j) {
    return (j << 8) | (T & 0xF0) | (((T >> 4) ^ T) & 0xF);
}

template<int K>
__device__ __forceinline__ void apply_u(float2* s, const float* u) {
    float u00r = u[0], u00i = u[1], u01r = u[2], u01i = u[3];
    float u10r = u[4], u10i = u[5], u11r = u[6], u11i = u[7];
    #pragma unroll
    for (int m = 0; m < 16; m++) {
        if (m & (1 << K)) continue;
        int j1 = m | (1 << K);
        float2 a0 = s[m], a1 = s[j1];
        s[m]  = make_float2(u00r * a0.x - u00i * a0.y + u01r * a1.x - u01i * a1.y,
                            u00r * a0.y + u00i * a0.x + u01r * a1.y + u01i * a1.x);
        s[j1] = make_float2(u10r * a0.x - u10i * a0.y + u11r * a1.x - u11i * a1.y,
                            u10r * a0.y + u10i * a0.x + u11r * a1.y + u11i * a1.x);
    }
}

template<int KC, int KT>
__device__ __forceinline__ void apply_cry_local(float2* s, float c, float sn) {
    #pragma unroll
    for (int m = 0; m < 16; m++) {
        if (!(m & (1 << KC)) || (m & (1 << KT))) continue;
        int j1 = m | (1 << KT);
        float2 a0 = s[m], a1 = s[j1];
        s[m]  = make_float2(c * a0.x - sn * a1.x, c * a0.y - sn * a1.y);
        s[j1] = make_float2(sn * a0.x + c * a1.x, sn * a0.y + c * a1.y);
    }
}

template<int KT>
__device__ __forceinline__ void apply_ry_all(float2* s, float c, float sn) {
    #pragma unroll
    for (int m = 0; m < 16; m++) {
        if (m & (1 << KT)) continue;
        int j1 = m | (1 << KT);
        float2 a0 = s[m], a1 = s[j1];
        s[m]  = make_float2(c * a0.x - sn * a1.x, c * a0.y - sn * a1.y);
        s[j1] = make_float2(sn * a0.x + c * a1.x, sn * a0.y + c * a1.y);
    }
}

#define XPOSE(SW, SR) do {                                        \
    __syncthreads();                                              \
    _Pragma("unroll") for (int j = 0; j < 16; j++) xch[SW(T, j)] = s[j]; \
    __syncthreads();                                              \
    _Pragma("unroll") for (int j = 0; j < 16; j++) s[j] = xch[SR(T, j)]; \
} while (0)

// Pin exactly 4 waves/EU: LDS (34 KB) caps us at 4 blocks/CU anyway, so give the
// allocator the full 128-VGPR budget. Round-3's __launch_bounds__(256,4) made the
// compiler target 8 waves/EU (VGPR=64) and spill s[16] -> 200 MB of scratch HBM traffic.
__attribute__((amdgpu_waves_per_eu(4, 4)))
__global__ void __launch_bounds__(256)
k_quantum(const float* __restrict__ enc,
          const float* __restrict__ bn1m, const float* __restrict__ bn1r,
          const float* __restrict__ g1, const float* __restrict__ b1,
          const float* __restrict__ gU, const float* __restrict__ gC,
          float* __restrict__ probs) {
    __shared__ float2 xch[NST];                                  // 32 KB
    __shared__ float  gbuf[DEPTH * NQ * 8 + DEPTH * (NQ - 1) * 2];  // 354
    __shared__ float  qv[NQ][2];
    __shared__ float  hbuf[NQ];

    int T = threadIdx.x, b = blockIdx.x;

    for (int i = T; i < 354; i += 256) gbuf[i] = (i < 288) ? gU[i] : gC[i - 288];

    if (T < NQ) {
        float e = enc[b * NQ + T];
        hbuf[T] = tanhf(g1[T] * (e - bn1m[T]) * bn1r[T] + b1[T]);
    }
    __syncthreads();
    if (T < NQ) {
        float n2 = 0.f;
        #pragma unroll
        for (int i = 0; i < NQ; i++) n2 += hbuf[i] * hbuf[i];
        float norm = sqrtf(n2);
        float h = hbuf[T];
        float a = (norm > 0.f) ? h / fmaxf(norm, 1e-30f) : h;
        float amp = fminf(fabsf(a), 1.f);
        float ch  = sqrtf(fmaxf(1.f - amp * amp, 0.f));
        qv[T][0] = ch;
        qv[T][1] = (a < 0.f) ? -amp : amp;
    }
    __syncthreads();

    // ---- initial product state, layout A ----
    float f = 1.f;
    #pragma unroll
    for (int q = 0; q < 8; q++) f *= qv[q][(T >> (7 - q)) & 1];
    float2 s[16];
    #pragma unroll
    for (int j = 0; j < 16; j++) {
        float p = f * qv[8][(j >> 3) & 1] * qv[9][(j >> 2) & 1]
                    * qv[10][(j >> 1) & 1] * qv[11][j & 1];
        s[j] = make_float2(p, 0.f);
    }

    #pragma unroll 1
    for (int l = 0; l < DEPTH; l++) {
        const float* UL = &gbuf[l * NQ * 8];
        const float* CL = &gbuf[288 + l * (NQ - 1) * 2];
        // layout A: U on qubits 8..11 (local bits 3..0)
        apply_u<3>(s, UL + 8 * 8);
        apply_u<2>(s, UL + 9 * 8);
        apply_u<1>(s, UL + 10 * 8);
        apply_u<0>(s, UL + 11 * 8);
        XPOSE(slotA, slotB);
        // layout B: U on qubits 4..7 (local bits 3..0 = idx bits 7..4)
        apply_u<3>(s, UL + 4 * 8);
        apply_u<2>(s, UL + 5 * 8);
        apply_u<1>(s, UL + 6 * 8);
        apply_u<0>(s, UL + 7 * 8);
        XPOSE(slotB, slotC);
        // layout C: U on qubits 0..3; CRY0..2
        apply_u<3>(s, UL + 0 * 8);
        apply_u<2>(s, UL + 1 * 8);
        apply_u<1>(s, UL + 2 * 8);
        apply_u<0>(s, UL + 3 * 8);
        apply_cry_local<3, 2>(s, CL[0], CL[1]);     // CRY0
        apply_cry_local<2, 1>(s, CL[2], CL[3]);     // CRY1
        apply_cry_local<1, 0>(s, CL[4], CL[5]);     // CRY2
        XPOSE(slotC, slotB);
        // layout B: CRY3..6 (CRY3 control = idx bit 8 = T[4])
        if (T & 16) apply_ry_all<3>(s, CL[6], CL[7]);   // CRY3
        apply_cry_local<3, 2>(s, CL[8], CL[9]);     // CRY4
        apply_cry_local<2, 1>(s, CL[10], CL[11]);   // CRY5
        apply_cry_local<1, 0>(s, CL[12], CL[13]);   // CRY6
        XPOSE(slotB, slotA);
        // layout A: CRY7..10 (CRY7 control = idx bit 4 = T[0])
        if (T & 1) apply_ry_all<3>(s, CL[14], CL[15]);  // CRY7
        apply_cry_local<3, 2>(s, CL[16], CL[17]);   // CRY8
        apply_cry_local<2, 1>(s, CL[18], CL[19]);   // CRY9
        apply_cry_local<1, 0>(s, CL[20], CL[21]);   // CRY10
    }

    // ---- marginals, layout A: idx = T<<4 | j ----
    float acc[NQ];
    float tot = 0.f;
    #pragma unroll
    for (int q = 8; q < NQ; q++) acc[q] = 0.f;
    #pragma unroll
    for (int j = 0; j < 16; j++) {
        float pr = s[j].x * s[j].x + s[j].y * s[j].y;
        tot += pr;
        if (j & 8) acc[8]  += pr;
        if (j & 4) acc[9]  += pr;
        if (j & 2) acc[10] += pr;
        if (j & 1) acc[11] += pr;
    }
    #pragma unroll
    for (int q = 0; q < 8; q++) acc[q] = ((T >> (7 - q)) & 1) ? tot : 0.f;

    #pragma unroll
    for (int q = 0; q < NQ; q++) {
        #pragma unroll
        for (int o = 32; o > 0; o >>= 1) acc[q] += __shfl_down(acc[q], o, 64);
    }
    __syncthreads();                     // xch no longer needed as state
    float* red = (float*)xch;
    int lane = T & 63, w = T >> 6;
    if (lane == 0) {
        #pragma unroll
        for (int q = 0; q < NQ; q++) red[w * NQ + q] = acc[q];
    }
    __syncthreads();
    if (T < NQ) probs[b * NQ + T] = red[T] + red[NQ + T] + red[2 * NQ + T] + red[3 * NQ + T];
}

// ================= K4: prob moments -> pmean + cov (one pass) =================
__global__ void k_pcov(const float* __restrict__ probs, float* __restrict__ pmean,
                       float* __restrict__ cov) {
    __shared__ float scr[8];
    int blk = blockIdx.x;             // 0..143
    int q = blk / NQ, q2 = blk % NQ;
    int t = threadIdx.x;
    float sx = 0.f, sy = 0.f, sxy = 0.f;
    for (int b = t; b < BATCH; b += 256) {
        float xv = probs[b * NQ + q];
        float yv = probs[b * NQ + q2];
        sx += xv; sy += yv; sxy += xv * yv;
    }
    float SX  = blockAllSum(sx,  scr);
    float SY  = blockAllSum(sy,  scr);
    float SXY = blockAllSum(sxy, scr);
    if (t == 0) {
        float mx = SX / (float)BATCH, my = SY / (float)BATCH;
        cov[blk] = SXY / (float)BATCH - mx * my;
        if (q == q2) pmean[q] = mx;
    }
}

// ================= K5: final decode + BN2 (rstd computed per-thread from cov) =================
// out[b,j] = (sum_q dw[j,q]*(p[b,q]-pmean[q])) * rstd[j] * g2[j] + b2[j], rstd = 1/sqrt(w^T C w + eps)
__global__ void k_final(const float* __restrict__ probs, const float* __restrict__ pmean,
                        const float* __restrict__ cov, const float* __restrict__ dw,
                        const float* __restrict__ g2, const float* __restrict__ b2,
                        float* __restrict__ out) {
    __shared__ float cv[NQ * NQ];
    __shared__ float cp[NQ];
    int b = blockIdx.x, t = threadIdx.x;      // t = output feature
    if (t < NQ * NQ) cv[t] = cov[t];
    if (t < NQ) cp[t] = probs[b * NQ + t] - pmean[t];
    __syncthreads();
    float w[NQ];
    #pragma unroll
    for (int q = 0; q < NQ; q++) w[q] = dw[t * NQ + q];
    float var = 0.f, acc = 0.f;
    #pragma unroll
    for (int q = 0; q < NQ; q++) {
        float a = 0.f;
        #pragma unroll
        for (int q2 = 0; q2 < NQ; q2++) a += cv[q * NQ + q2] * w[q2];
        var += w[q] * a;
        acc += cp[q] * w[q];
    }
    out[b * OUT_SZ + t] = acc * (1.f / sqrtf(var + BN_EPS)) * g2[t] + b2[t];
}

extern "C" void kernel_launch(void* const* d_in, const int* in_sizes, int n_in,
                              void* d_out, int out_size, void* d_ws, size_t ws_size,
                              hipStream_t stream) {
    const float* x     = (const float*)d_in[0];
    const float* enc_w = (const float*)d_in[1];
    const float* enc_b = (const float*)d_in[2];
    const float* rot   = (const float*)d_in[3];
    const float* ent   = (const float*)d_in[4];
    const float* dec_w = (const float*)d_in[5];
    // d_in[6] = dec_b — cancels inside BN2
    const float* g1    = (const float*)d_in[7];
    const float* b1    = (const float*)d_in[8];
    const float* g2    = (const float*)d_in[9];
    const float* b2    = (const float*)d_in[10];

    float* ws    = (float*)d_ws;
    float* enc   = ws + OFF_ENC;
    float* bn1m  = ws + OFF_BN1M;
    float* bn1r  = ws + OFF_BN1R;
    float* gU    = ws + OFF_GU;
    float* gC    = ws + OFF_GC;
    float* prb   = ws + OFF_PROBS;
    float* pmean = ws + OFF_PMEAN;
    float* cov   = ws + OFF_COV;

    hipLaunchKernelGGL(k_encode, dim3(193), dim3(256), 0, stream,
                       x, enc_w, enc_b, rot, ent, enc, gU, gC);
    hipLaunchKernelGGL(k_bnstats, dim3(NQ), dim3(256), 0, stream, enc, bn1m, bn1r, NQ, BATCH);
    hipLaunchKernelGGL(k_quantum, dim3(BATCH), dim3(256), 0, stream,
                       enc, bn1m, bn1r, g1, b1, gU, gC, prb);
    hipLaunchKernelGGL(k_pcov, dim3(NQ * NQ), dim3(256), 0, stream, prb, pmean, cov);
    hipLaunchKernelGGL(k_final, dim3(BATCH), dim3(OUT_SZ), 0, stream,
                       prb, pmean, cov, dec_w, g2, b2, (float*)d_out);
}